// Round 8
// baseline (283.930 us; speedup 1.0000x reference)
//
#include <hip/hip_runtime.h>
#include <hip/hip_bf16.h>
#include <math.h>

// Problem: B=2, T=2048, D_MODEL=1024, H=16, HD=64.
// I/O FP32; internal bf16 MFMA.
// R8: attn = R5 compute + register-prefetch staging (hide HBM/L2 latency across
// compute phase); RoPE cos/sin table (kills 2M libm sincosf); out-GEMM BM=64
// (512 blocks, was 256=1/CU); fused weight cvt.
// Workspace (~40.5MB): [qkv 12M][xn/vt 4M][wqkvb 3M][woutb 1M] bf16 + cos/sin tab 128K f32.

typedef __bf16 bf16;
typedef __bf16 bf16x8 __attribute__((ext_vector_type(8)));
typedef __bf16 bf16x4 __attribute__((ext_vector_type(4)));
typedef float  f32x4  __attribute__((ext_vector_type(4)));

#define GLOAD16(g, l) __builtin_amdgcn_global_load_lds( \
    (const __attribute__((address_space(1))) void*)(g),  \
    (__attribute__((address_space(3))) void*)(l), 16, 0, 0)

__device__ __forceinline__ unsigned pk2(float a, float b) {
  unsigned short lo = __builtin_bit_cast(unsigned short, (bf16)a);
  unsigned short hi = __builtin_bit_cast(unsigned short, (bf16)b);
  return (unsigned)lo | ((unsigned)hi << 16);
}

// ---------------- fused fp32 -> bf16 weight conversion ----------------
__global__ __launch_bounds__(256) void k_cvt2(const float* __restrict__ srcA,
    const float* __restrict__ srcB, bf16* __restrict__ dst, int nA, int nTot) {
  int i = (blockIdx.x * 256 + threadIdx.x) * 8;
  if (i >= nTot) return;
  const float* s = (i < nA) ? (srcA + i) : (srcB + (i - nA));
  float4 a = *(const float4*)(s);
  float4 b = *(const float4*)(s + 4);
  bf16x8 o;
  o[0] = (bf16)a.x; o[1] = (bf16)a.y; o[2] = (bf16)a.z; o[3] = (bf16)a.w;
  o[4] = (bf16)b.x; o[5] = (bf16)b.y; o[6] = (bf16)b.z; o[7] = (bf16)b.w;
  *(bf16x8*)(dst + i) = o;
}

// ---------------- RoPE cos/sin table: [2048 t][32 f] fp32 ----------------
__global__ __launch_bounds__(256) void k_tab(float* __restrict__ cs,
    float* __restrict__ sn) {
  int idx = blockIdx.x * 256 + threadIdx.x;   // 65536
  int t = idx >> 5, f = idx & 31;
  float invf = exp2f(-0.41524101186f * (float)f);  // 1e4^(-f/32)
  float th = (float)t * invf;
  float s, c;
  sincosf(th, &s, &c);     // libm: exact range reduction (th up to 2047 rad)
  cs[idx] = c; sn[idx] = s;
}

// ---------------- RMSNorm: x[4096][1024] f32 -> xn bf16 ----------------
__global__ __launch_bounds__(256) void k_rmsnorm(const float* __restrict__ x,
    const float* __restrict__ w, bf16* __restrict__ xn) {
  const int row = blockIdx.x, tid = threadIdx.x;
  float4 v = *(const float4*)(x + (size_t)row * 1024 + tid * 4);
  float ss = v.x * v.x + v.y * v.y + v.z * v.z + v.w * v.w;
  for (int m = 32; m >= 1; m >>= 1) ss += __shfl_xor(ss, m);
  __shared__ float red[4];
  if ((tid & 63) == 0) red[tid >> 6] = ss;
  __syncthreads();
  float ms = (red[0] + red[1] + red[2] + red[3]) * (1.f / 1024.f);
  float r = rsqrtf(ms + 1e-5f);
  float4 wv = *(const float4*)(w + tid * 4);
  bf16x4 o;
  o[0] = (bf16)(v.x * r * wv.x); o[1] = (bf16)(v.y * r * wv.y);
  o[2] = (bf16)(v.z * r * wv.z); o[3] = (bf16)(v.w * r * wv.w);
  *(bf16x4*)(xn + (size_t)row * 1024 + tid * 4) = o;
}

// ---------------- GEMM: C[M][N] = A[M][K](lda) @ B[N][K]^T, bf16 inputs ----------------
// RESID=0: C bf16.  RESID=1: C fp32 + fp32 residual R.  BM in {64,128}; BN=128.
template<int RESID, int BM>
__global__ __launch_bounds__(256, 2) void k_gemm_bt(const bf16* __restrict__ A,
    const bf16* __restrict__ B, const float* __restrict__ R, void* __restrict__ Cv,
    int M, int N, int K, int lda) {
  constexpr int MT = BM / 32;               // m-frags per wave
  constexpr int SMEM = (BM == 128) ? 17408 : 12288;
  const int tid = threadIdx.x;
  const int lane = tid & 63, L15 = lane & 15, quad = lane >> 4;
  const int wave = tid >> 6, wr = wave >> 1, wc = wave & 1;
  const int n0 = blockIdx.x * 128, m0 = blockIdx.y * BM;
  __shared__ __align__(16) bf16 smem[SMEM];
  bf16* sA = smem; bf16* sB = smem + BM * 64;
  f32x4 acc[MT][4];
  const f32x4 z = {0.f, 0.f, 0.f, 0.f};
  for (int i = 0; i < MT; i++) for (int j = 0; j < 4; j++) acc[i][j] = z;

  for (int k0 = 0; k0 < K; k0 += 64) {
    const bf16* Ab = A + (size_t)m0 * lda + k0;
    const bf16* Bb = B + (size_t)n0 * K + k0;
    for (int p = 0; p < MT; p++) {      // A: BM rows x 8 chunks(16B)
      int s = p * 256 + tid, r = s >> 3, c8 = (s & 7) ^ (r & 7);
      GLOAD16(Ab + (size_t)r * lda + c8 * 8, sA + s * 8);
    }
    for (int p = 0; p < 4; p++) {       // B: 128 rows x 8 chunks(16B)
      int s = p * 256 + tid, r = s >> 3, c8 = (s & 7) ^ (r & 7);
      GLOAD16(Bb + (size_t)r * K + c8 * 8, sB + s * 8);
    }
    __syncthreads();
    for (int kk = 0; kk < 2; kk++) {
      bf16x8 af[MT], bfv[4];
      for (int i = 0; i < MT; i++) {
        int ra = wr * (BM / 2) + i * 16 + L15;
        af[i] = *(const bf16x8*)(sA + ra * 64 + (((kk * 4 + quad) ^ (ra & 7)) * 8));
      }
      for (int i = 0; i < 4; i++) {
        int rb = wc * 64 + i * 16 + L15;
        bfv[i] = *(const bf16x8*)(sB + rb * 64 + (((kk * 4 + quad) ^ (rb & 7)) * 8));
      }
      for (int mt = 0; mt < MT; mt++)
        for (int nt = 0; nt < 4; nt++)
          acc[mt][nt] = __builtin_amdgcn_mfma_f32_16x16x32_bf16(af[mt], bfv[nt], acc[mt][nt], 0, 0, 0);
    }
    __syncthreads();
  }
  // epilogue: LDS transpose (bf16) for coalesced stores
  bf16* sC = smem;   // [BM][136]
  for (int mt = 0; mt < MT; mt++) for (int nt = 0; nt < 4; nt++) {
    int r = wr * (BM / 2) + mt * 16 + quad * 4, c = wc * 64 + nt * 16 + L15;
    f32x4 v = acc[mt][nt];
    for (int g = 0; g < 4; g++) sC[(r + g) * 136 + c] = (bf16)v[g];
  }
  __syncthreads();
  constexpr int TPR = 256 / BM;             // threads per row
  constexpr int CPT = 128 / TPR;            // cols per thread
  const int rr = tid / TPR, sg = (tid % TPR) * CPT;
  const size_t row = (size_t)m0 + rr;
  const bf16* src = sC + rr * 136 + sg;
  if (RESID) {   // fp32 out + fp32 residual
    float* Cf = (float*)Cv;
    const float* rs = R + row * N + n0 + sg;
    float* dst = Cf + row * N + n0 + sg;
    for (int i = 0; i < CPT / 4; i++) {
      bf16x4 u = *(const bf16x4*)(src + i * 4);
      float4 rv = *(const float4*)(rs + i * 4);
      float4 o;
      o.x = (float)u[0] + rv.x; o.y = (float)u[1] + rv.y;
      o.z = (float)u[2] + rv.z; o.w = (float)u[3] + rv.w;
      *(float4*)(dst + i * 4) = o;
    }
  } else {       // bf16 out
    bf16* Cb = (bf16*)Cv;
    bf16* dst = Cb + row * N + n0 + sg;
    for (int i = 0; i < CPT / 8; i++)
      *(bf16x8*)(dst + i * 8) = *(const bf16x8*)(src + i * 8);
  }
}

// ---------------- RoPE in-place on qkv Q/K slots (table-driven); V -> vt[bh][d][t] ----------------
__global__ __launch_bounds__(256) void k_rope(bf16* __restrict__ qkv,
    bf16* __restrict__ vt, const float* __restrict__ cs, const float* __restrict__ sn) {
  const int blk = blockIdx.x;
  const int tt = blk & 31, h = (blk >> 5) & 15, b = blk >> 9;
  const int tid = threadIdx.x;
  const int bh = b * 16 + h;
  { // phase A: rope q,k in place. 64 t x 4 d-chunk pairs (d, d+32)
    const int tl = tid >> 2, dp = (tid & 3) * 8;
    const int tg = tt * 64 + tl;
    bf16* base = qkv + (size_t)(b * 2048 + tg) * 3072 + h * 64;
    bf16x8 qlo = *(const bf16x8*)(base + dp);
    bf16x8 qhi = *(const bf16x8*)(base + dp + 32);
    bf16x8 klo = *(const bf16x8*)(base + 1024 + dp);
    bf16x8 khi = *(const bf16x8*)(base + 1024 + dp + 32);
    float cb[8], sb[8];
    *(float4*)(cb)     = *(const float4*)(cs + tg * 32 + dp);
    *(float4*)(cb + 4) = *(const float4*)(cs + tg * 32 + dp + 4);
    *(float4*)(sb)     = *(const float4*)(sn + tg * 32 + dp);
    *(float4*)(sb + 4) = *(const float4*)(sn + tg * 32 + dp + 4);
    bf16x8 oql, oqh, okl, okh;
    for (int j = 0; j < 8; j++) {
      float csv = cb[j], snv = sb[j];
      float a0 = (float)qlo[j], a1 = (float)qhi[j];
      float b0 = (float)klo[j], b1 = (float)khi[j];
      oql[j] = (bf16)(a0 * csv - a1 * snv);
      oqh[j] = (bf16)(a1 * csv + a0 * snv);
      okl[j] = (bf16)(b0 * csv - b1 * snv);
      okh[j] = (bf16)(b1 * csv + b0 * snv);
    }
    *(bf16x8*)(base + dp) = oql; *(bf16x8*)(base + dp + 32) = oqh;
    *(bf16x8*)(base + 1024 + dp) = okl; *(bf16x8*)(base + 1024 + dp + 32) = okh;
  }
  // phase B: transpose V tile 64t x 64d -> vt[bh][d][t]
  __shared__ __align__(16) bf16 sT[64 * 72];
  for (int p = 0; p < 2; p++) {
    int s = p * 256 + tid, tl = s >> 3, c = s & 7;
    const bf16* vsrc = qkv + (size_t)(b * 2048 + tt * 64 + tl) * 3072 + 2048 + h * 64 + c * 8;
    *(bf16x8*)(sT + tl * 72 + c * 8) = *(const bf16x8*)vsrc;
  }
  __syncthreads();
  for (int p = 0; p < 2; p++) {
    int s = p * 256 + tid, d = s >> 3, tc = s & 7;
    bf16x8 v;
    for (int j = 0; j < 8; j++) v[j] = sT[(tc * 8 + j) * 72 + d];
    *(bf16x8*)(vt + (size_t)bh * 131072 + (size_t)d * 2048 + tt * 64 + tc * 8) = v;
  }
}

// ---------------- Flash attention: R5 compute + register-prefetch staging ----------------
// S^T = K*Q^T (C-layout row=kv, col=q); O^T = V^T*P^T via sP round-trip (per-wave rows).
// Staging: next K/V tile -> 8 uint4 VGPRs during compute, ds_write at iter top.
// The vmcnt(0) drain thus overlaps a full compute phase instead of stalling the barrier.
__global__ __launch_bounds__(256, 2) void k_attn(bf16* __restrict__ qkv,
    const bf16* __restrict__ vt) {
  const int tid = threadIdx.x;
  const int lane = tid & 63, L15 = lane & 15, quad = lane >> 4;
  const int wave = tid >> 6;
  const int bh = blockIdx.y, b = bh >> 4, h = bh & 15;
  const int q0 = blockIdx.x * 128;
  const bf16* Q  = qkv + (size_t)b * 2048 * 3072 + h * 64;           // + t*3072
  const bf16* Kg = qkv + (size_t)b * 2048 * 3072 + 1024 + h * 64;    // + t*3072
  const bf16* Vg = vt + (size_t)bh * 131072;                         // [d][2048]
  __shared__ __align__(16) bf16 sK[8192];     // [128 kv][64 d] swizzled
  __shared__ __align__(16) bf16 sV[8192];     // [64 d][128 kv] swizzled
  __shared__ __align__(16) bf16 sP[17408];    // [128 q][136 kv] (272B rows)

  // per-thread staging offsets (constant across iters)
  int koff[4], voff[4], sidx[4];
  for (int p = 0; p < 4; p++) {
    int s = p * 256 + tid;
    sidx[p] = s * 8;
    { int r = s >> 3, c8 = (s & 7) ^ (r & 7); koff[p] = r * 3072 + c8 * 8; }
    { int r = s >> 4, cl = s & 15; int c8 = (cl & 8) | ((cl ^ (r & 7)) & 7);
      voff[p] = r * 2048 + c8 * 8; }
  }
  uint4 rK[4], rV[4];
  {  // prologue: tile 0 into regs
    const bf16* Kb = Kg;  const bf16* Vb = Vg;
    #pragma unroll
    for (int p = 0; p < 4; p++) {
      rK[p] = *(const uint4*)(Kb + koff[p]);
      rV[p] = *(const uint4*)(Vb + voff[p]);
    }
  }

  bf16x8 qf[2][2];  // b-operand frags: Q[q][d], once per block
  for (int qt = 0; qt < 2; qt++) for (int kk = 0; kk < 2; kk++) {
    int rq = q0 + wave * 32 + qt * 16 + L15;
    qf[qt][kk] = *(const bf16x8*)(Q + (size_t)rq * 3072 + kk * 32 + quad * 8);
  }
  f32x4 o[4][2];
  const f32x4 z = {0.f, 0.f, 0.f, 0.f};
  for (int i = 0; i < 4; i++) for (int j = 0; j < 2; j++) o[i][j] = z;
  float lpart[2] = {0.f, 0.f};
  const float SC = 0.125f * 1.44269504f;    // 1/sqrt(64) * log2(e)

  for (int kv0 = 0; kv0 < 2048; kv0 += 128) {
    __syncthreads();   // previous iter's sK/sV reads complete
    #pragma unroll
    for (int p = 0; p < 4; p++) {       // regs -> LDS (waits vmcnt here, post-compute)
      *(uint4*)(sK + sidx[p]) = rK[p];
      *(uint4*)(sV + sidx[p]) = rV[p];
    }
    __syncthreads();   // sK/sV visible to all waves
    {  // prefetch next tile into regs (safe over-read on last iter: ws has slack)
      const bf16* Kb = Kg + (size_t)(kv0 + 128) * 3072;
      const bf16* Vb = Vg + (kv0 + 128);
      #pragma unroll
      for (int p = 0; p < 4; p++) {
        rK[p] = *(const uint4*)(Kb + koff[p]);
        rV[p] = *(const uint4*)(Vb + voff[p]);
      }
    }
    f32x4 st[8][2];
    for (int i = 0; i < 8; i++) for (int j = 0; j < 2; j++) st[i][j] = z;
    for (int kk = 0; kk < 2; kk++) {
      bf16x8 kf[8];
      for (int kvt = 0; kvt < 8; kvt++) {
        int rk = kvt * 16 + L15;
        kf[kvt] = *(const bf16x8*)(sK + rk * 64 + (((kk * 4 + quad) ^ (rk & 7)) * 8));
      }
      for (int kvt = 0; kvt < 8; kvt++)
        for (int qt = 0; qt < 2; qt++)
          st[kvt][qt] = __builtin_amdgcn_mfma_f32_16x16x32_bf16(kf[kvt], qf[qt][kk], st[kvt][qt], 0, 0, 0);
    }
    // shift-free softmax numerator: p = exp2(s*SC); per-lane partial l
    for (int qt = 0; qt < 2; qt++) {
      float ls = 0.f;
      int rq = wave * 32 + qt * 16 + L15;
      for (int kvt = 0; kvt < 8; kvt++) {
        float p0 = exp2f(st[kvt][qt][0] * SC);
        float p1 = exp2f(st[kvt][qt][1] * SC);
        float p2 = exp2f(st[kvt][qt][2] * SC);
        float p3 = exp2f(st[kvt][qt][3] * SC);
        ls += (p0 + p1) + (p2 + p3);
        uint2 w2; w2.x = pk2(p0, p1); w2.y = pk2(p2, p3);
        *(uint2*)(sP + rq * 136 + kvt * 16 + quad * 4) = w2;
      }
      lpart[qt] += ls;
    }
    // O^T += V^T @ P^T (wave reads only its own P rows)
    for (int kc = 0; kc < 4; kc++) {
      bf16x8 vf[4], pf[2];
      for (int dt = 0; dt < 4; dt++) {
        int rd = dt * 16 + L15;
        int c = kc * 4 + quad;
        int cs = (c & 8) | ((c ^ (rd & 7)) & 7);
        vf[dt] = *(const bf16x8*)(sV + rd * 128 + cs * 8);
      }
      for (int qt = 0; qt < 2; qt++) {
        int rq = wave * 32 + qt * 16 + L15;
        pf[qt] = *(const bf16x8*)(sP + rq * 136 + kc * 32 + quad * 8);
      }
      for (int dt = 0; dt < 4; dt++)
        for (int qt = 0; qt < 2; qt++)
          o[dt][qt] = __builtin_amdgcn_mfma_f32_16x16x32_bf16(vf[dt], pf[qt], o[dt][qt], 0, 0, 0);
    }
  }
  float invl[2];
  for (int qt = 0; qt < 2; qt++) {
    float l = lpart[qt];
    l += __shfl_xor(l, 16);
    l += __shfl_xor(l, 32);
    invl[qt] = 1.f / l;
  }
  __syncthreads();               // sP alias: all waves done with PV reads
  bf16* sO = sP;                 // [128 q][72 d]
  for (int dt = 0; dt < 4; dt++) for (int qt = 0; qt < 2; qt++) {
    f32x4 v = o[dt][qt] * invl[qt];
    int ql = wave * 32 + qt * 16 + L15;
    uint2 w2; w2.x = pk2(v[0], v[1]); w2.y = pk2(v[2], v[3]);
    *(uint2*)(sO + ql * 72 + dt * 16 + quad * 4) = w2;
  }
  __syncthreads();
  const int rr = tid >> 1, sg = (tid & 1) * 32;
  const bf16* src = sO + rr * 72 + sg;
  bf16* dst = qkv + (size_t)(b * 2048 + q0 + rr) * 3072 + h * 64 + sg;  // Q slot
  for (int i = 0; i < 4; i++)
    *(bf16x8*)(dst + i * 8) = *(const bf16x8*)(src + i * 8);
}

extern "C" void kernel_launch(void* const* d_in, const int* in_sizes, int n_in,
                              void* d_out, int out_size, void* d_ws, size_t ws_size,
                              hipStream_t stream) {
  (void)in_sizes; (void)n_in; (void)out_size;
  const float* x     = (const float*)d_in[0];
  const float* normw = (const float*)d_in[1];
  const float* wqkv  = (const float*)d_in[2];
  const float* wout  = (const float*)d_in[3];
  float* out = (float*)d_out;
  bf16* ws  = (bf16*)d_ws;
  const size_t NQKV = (size_t)4096 * 3072, NXN = (size_t)4096 * 1024;
  const size_t NWQ = (size_t)3072 * 1024, NWO = (size_t)1024 * 1024;
  const size_t NTAB = 65536;  // floats per table
  const size_t need = (NQKV + NXN + NWQ + NWO) * sizeof(bf16) + 2 * NTAB * sizeof(float);
  if (ws_size < need) return;
  bf16* qkv    = ws;
  bf16* xn     = qkv + NQKV;    // reused as vt after qkv gemm consumes xn
  bf16* vtp    = xn;
  bf16* wqkvb  = xn + NXN;
  bf16* woutb  = wqkvb + NWQ;
  float* tabc  = (float*)(woutb + NWO);
  float* tabs  = tabc + NTAB;
  k_cvt2<<<(int)((NWQ + NWO) / 8 / 256), 256, 0, stream>>>(wqkv, wout, wqkvb, (int)NWQ, (int)(NWQ + NWO));
  k_tab<<<256, 256, 0, stream>>>(tabc, tabs);
  k_rmsnorm<<<4096, 256, 0, stream>>>(x, normw, xn);
  k_gemm_bt<0, 128><<<dim3(24, 32), 256, 0, stream>>>(xn, wqkvb, nullptr, qkv, 4096, 3072, 1024, 1024);
  k_rope<<<1024, 256, 0, stream>>>(qkv, vtp, tabc, tabs);
  k_attn<<<dim3(16, 32), 256, 0, stream>>>(qkv, vtp);
  k_gemm_bt<1, 64><<<dim3(8, 64), 256, 0, stream>>>(qkv, woutb, x, out, 4096, 1024, 1024, 3072);
}